// Round 10
// baseline (139.882 us; speedup 1.0000x reference)
//
#include <hip/hip_runtime.h>

#define NB 32
#define NN 64
#define ND 128
#define NE 128
#define NK 64   // output capsules (= NN)

typedef float  f32x4  __attribute__((ext_vector_type(4)));
typedef short  short8 __attribute__((ext_vector_type(8)));
typedef __bf16 bf16x8 __attribute__((ext_vector_type(8)));

union Frag { bf16x8 h; short8 s; };

// u layout: [j][d][b][k]  -- wave-(j,d) output tile is one contiguous 4KB run
static constexpr size_t U_BYTES = (size_t)NN * ND * NB * NK * 2;  // 33.5 MB
static constexpr size_t V_BYTES = (size_t)NB * ND * NK * 4;       // 1 MB
static constexpr size_t WS_NEED = U_BYTES + 2 * V_BYTES;

#define GLOAD16(g, l)                                                   \
    __builtin_amdgcn_global_load_lds(                                   \
        (const __attribute__((address_space(1))) void*)(g),             \
        (__attribute__((address_space(3))) void*)(l), 16, 0, 0)

// ---------------- DPP wave64 sum (VALU pipe) ----------------
template <int CTRL, int RMASK>
__device__ __forceinline__ float dppf(float x) {
    int xi = __float_as_int(x);
    return __int_as_float(__builtin_amdgcn_update_dpp(xi, xi, CTRL, RMASK, 0xF, false));
}
__device__ __forceinline__ float wave_sum(float x) {
    x += dppf<0xB1, 0xF>(x);   // quad_perm [1,0,3,2]
    x += dppf<0x4E, 0xF>(x);   // quad_perm [2,3,0,1]
    x += dppf<0x141, 0xF>(x);  // row_half_mirror
    x += dppf<0x140, 0xF>(x);  // row_mirror
    x += dppf<0x142, 0xA>(x);  // row_bcast15 -> rows 1,3
    x += dppf<0x143, 0xC>(x);  // row_bcast31 -> rows 2,3
    return __int_as_float(__builtin_amdgcn_readlane(__float_as_int(x), 63));
}

__device__ __forceinline__ ushort f2bf(float f) {
    __bf16 h = (__bf16)f;
    ushort r;
    __builtin_memcpy(&r, &h, 2);
    return r;
}
__device__ __forceinline__ float bf2f(ushort r) {
    return __int_as_float(((int)r) << 16);
}
__device__ __forceinline__ void cvt8(const float4& a, const float4& b, Frag& fr) {
    fr.h[0] = (__bf16)a.x; fr.h[1] = (__bf16)a.y; fr.h[2] = (__bf16)a.z; fr.h[3] = (__bf16)a.w;
    fr.h[4] = (__bf16)b.x; fr.h[5] = (__bf16)b.y; fr.h[6] = (__bf16)b.z; fr.h[7] = (__bf16)b.w;
}

// ---------------- K0: zero s (kernel, NOT a fill node) ---------------------
__global__ __launch_bounds__(256) void k_zero(float* __restrict__ s) {
    reinterpret_cast<f32x4*>(s)[blockIdx.x * 256 + threadIdx.x] = (f32x4)0.0f;
}

// ---------------- K1: u[j,d,b,k] = sum_e x[b,j,e] * W[j,k,d,e] (bf16 MFMA) --
// r7 structure (best measured). NEW: fuses routing pass 1 -- each wave
// atomicAdds acc/64 into s[b][d][k] (uniform-softmax weighted sum), saving
// the 33.5 MB u-read of the first k_route on a read-BW-capped chip.
__global__ __launch_bounds__(256, 3) void k_u(const float* __restrict__ W,
                                              const float* __restrict__ x,
                                              ushort* __restrict__ u,
                                              float* __restrict__ s) {
    __shared__ float  Wl[4][2][1024];  // per-wave double-buffered 4KB chunks
    __shared__ ushort T[4][32][72];    // per-wave [b][k] transpose tile
    const int t  = threadIdx.x;
    const int wv = t >> 6;
    const int l  = t & 63;
    const int gw = blockIdx.x * 4 + wv;
    const int j  = gw >> 7;
    const int d  = gw & 127;

    const int lr = l & 15;  // fragment row/col index
    const int lh = l >> 4;  // 0..3
    const int e0 = lh * 8;

    // ---- A fragments: x[b, j, e], row = b (VGPR loads; x is small & L2-hot)
    const float* xb = x + (size_t)j * NE;
    float4 xf[2][4][2];
#pragma unroll
    for (int mt = 0; mt < 2; ++mt)
#pragma unroll
        for (int ec = 0; ec < 4; ++ec) {
            const float* p = xb + (size_t)(mt * 16 + lr) * (NN * NE) + ec * 32 + e0;
            xf[mt][ec][0] = *reinterpret_cast<const float4*>(p);
            xf[mt][ec][1] = *reinterpret_cast<const float4*>(p + 4);
        }
    // drain A-loads so chunk vmcnt bookkeeping below is exact
    asm volatile("s_waitcnt vmcnt(0)" ::: "memory");
    __builtin_amdgcn_sched_barrier(0);
    Frag a[2][4];
#pragma unroll
    for (int mt = 0; mt < 2; ++mt)
#pragma unroll
        for (int ec = 0; ec < 4; ++ec) cvt8(xf[mt][ec][0], xf[mt][ec][1], a[mt][ec]);

    // ---- W staging: chunk c=(nt,eh): k rows nt*16..+15, e floats eh*64..+63
    const char* Wg = (const char*)W + ((size_t)(j * NN) * ND + d) * (NE * 4);
#define STAGE(c, buf)                                                       \
    {                                                                       \
        const int nt_ = (c) >> 1, eh_ = (c) & 1;                            \
        const char* gp_ = Wg + (size_t)(nt_ * 16 + lr) * 65536 + eh_ * 256; \
        _Pragma("unroll") for (int i_ = 0; i_ < 4; ++i_)                    \
            GLOAD16(gp_ + (i_ * 4 + lh) * 16, &Wl[wv][buf][i_ * 256]);      \
    }

    STAGE(0, 0);
    STAGE(1, 1);

    f32x4 acc[2][4];
#pragma unroll
    for (int mt = 0; mt < 2; ++mt)
#pragma unroll
        for (int nt = 0; nt < 4; ++nt) acc[mt][nt] = (f32x4)0.0f;

#pragma unroll
    for (int c = 0; c < 8; ++c) {
        const int nt = c >> 1, eh = c & 1, buf = c & 1;
        if (c < 7) { asm volatile("s_waitcnt vmcnt(4)" ::: "memory"); }
        else       { asm volatile("s_waitcnt vmcnt(0)" ::: "memory"); }
        __builtin_amdgcn_sched_barrier(0);

        const float* cb = &Wl[wv][buf][0];
        f32x4 g[2][2];
#pragma unroll
        for (int ec = 0; ec < 2; ++ec) {
            const int sl = (ec * 8 + lh * 2) * 64 + lr * 4;
            g[ec][0] = *reinterpret_cast<const f32x4*>(cb + sl);
            g[ec][1] = *reinterpret_cast<const f32x4*>(cb + sl + 64);
        }
        // ds_reads must land before this buffer is re-staged (rule #18)
        asm volatile("s_waitcnt lgkmcnt(0)" ::: "memory");
        __builtin_amdgcn_sched_barrier(0);
        if (c < 6) STAGE(c + 2, buf);

#pragma unroll
        for (int ec = 0; ec < 2; ++ec) {
            Frag bw;
            float4 f0 = {g[ec][0][0], g[ec][0][1], g[ec][0][2], g[ec][0][3]};
            float4 f1 = {g[ec][1][0], g[ec][1][1], g[ec][1][2], g[ec][1][3]};
            cvt8(f0, f1, bw);
#pragma unroll
            for (int mt = 0; mt < 2; ++mt)
                acc[mt][nt] = __builtin_amdgcn_mfma_f32_16x16x32_bf16(
                    a[mt][eh * 2 + ec].s, bw.s, acc[mt][nt], 0, 0, 0);
        }
    }
#undef STAGE

    // ---- FUSED routing pass 1: s[b][d][k] += acc/64 (uniform softmax).
    // D frag: row=b=(l>>4)*4+r (+16*mt), col=k=lr (+16*nt)  [m89 layout]
    // Target is 1MB -> L2-resident RMW; 32 atomic instrs per wave.
#pragma unroll
    for (int mt = 0; mt < 2; ++mt)
#pragma unroll
        for (int nt = 0; nt < 4; ++nt)
#pragma unroll
            for (int r = 0; r < 4; ++r) {
                const int b  = mt * 16 + lh * 4 + r;
                const int kk = nt * 16 + lr;
                atomicAdd(&s[((size_t)b * ND + d) * NK + kk],
                          acc[mt][nt][r] * (1.0f / 64.0f));
            }

    // epilogue: u-tile transpose + contiguous 4KB write (verbatim r7)
#pragma unroll
    for (int mt = 0; mt < 2; ++mt)
#pragma unroll
        for (int nt = 0; nt < 4; ++nt)
#pragma unroll
            for (int r = 0; r < 4; ++r)
                T[wv][mt * 16 + lh * 4 + r][nt * 16 + lr] = f2bf(acc[mt][nt][r]);
    __syncthreads();

    const int b2 = l >> 1;
    const int kh = (l & 1) * 32;
    ushort* up = u + (((size_t)j * ND + d) * NB + b2) * NK + kh;
    const ushort* tp = &T[wv][b2][kh];
#pragma unroll
    for (int i = 0; i < 4; ++i) {
        short8 v = *reinterpret_cast<const short8*>(tp + i * 8);
        *reinterpret_cast<short8*>(up + i * 8) = v;
    }
}

// ---------------- Routing: s[b,d,k] = sum_j softmax_k(u*Vsum) * u ----------
// (verbatim r7, always first=0 now; u is [j][d][b][k])
__global__ __launch_bounds__(512) void k_route(const ushort* __restrict__ u,
                                               const float* __restrict__ Vsum,
                                               float* __restrict__ s) {
    __shared__ float P[8][8][65];
    const int b  = blockIdx.x >> 4;
    const int dg = blockIdx.x & 15;
    const int t  = threadIdx.x;
    const int wv = t >> 6;  // j-group
    const int l  = t & 63;  // k

    float sacc[8];
#pragma unroll
    for (int dd = 0; dd < 8; ++dd) sacc[dd] = 0.0f;

    const size_t JS = (size_t)ND * NB * NK;
    const ushort* ub = u + ((size_t)(wv * 8) * ND + dg * 8) * (NB * NK) +
                       (size_t)b * NK + l;

    float vs[8];
#pragma unroll
    for (int dd = 0; dd < 8; ++dd)
        vs[dd] = Vsum[((size_t)b * ND + dg * 8 + dd) * NK + l];

    for (int jj = 0; jj < 8; ++jj) {
        const ushort* up = ub + jj * JS;
        float uv[8];
#pragma unroll
        for (int dd = 0; dd < 8; ++dd) uv[dd] = bf2f(up[dd * (NB * NK)]);
#pragma unroll
        for (int dd = 0; dd < 8; ++dd) {
            // softmax is shift-invariant; constant shift avoids overflow
            float p = __expf(uv[dd] * vs[dd] - 32.0f);
            float q = wave_sum(p);
            sacc[dd] = fmaf(p * __builtin_amdgcn_rcpf(q), uv[dd], sacc[dd]);
        }
    }

#pragma unroll
    for (int dd = 0; dd < 8; ++dd) P[wv][dd][l] = sacc[dd];
    __syncthreads();

    const int dd = t >> 6;
    const int k  = t & 63;
    float r = P[0][dd][k];
#pragma unroll
    for (int w2 = 1; w2 < 8; ++w2) r += P[w2][dd][k];
    s[((size_t)b * ND + dg * 8 + dd) * NK + k] = r;
}

// ---------------- Squash (verbatim r7) -------------------------------------
// mode 0: Vsum = v (init, no read)   mode 1: Vsum += v   mode 2: out = v
__global__ __launch_bounds__(256) void k_squash(const float* __restrict__ s,
                                                float* __restrict__ Vsum,
                                                float* __restrict__ out,
                                                int mode) {
    const int t  = threadIdx.x;
    const int gw = blockIdx.x * 4 + (t >> 6);
    const int b  = gw >> 6;
    const int k  = gw & 63;
    const int l  = t & 63;

    const float s0 = s[((size_t)b * ND + l) * NK + k];
    const float s1 = s[((size_t)b * ND + l + 64) * NK + k];
    float sq    = wave_sum(fmaf(s0, s0, s1 * s1));
    float scale = (sq / (1.0f + sq)) * rsqrtf(sq + 1e-9f);
    float v0 = s0 * scale, v1 = s1 * scale;
    if (mode == 2) {
        float* op = out + ((size_t)b * NN + k) * ND;
        op[l]      = v0;
        op[l + 64] = v1;
    } else if (mode == 0) {
        float* vp = Vsum + (size_t)b * ND * NK + k;
        vp[(size_t)l * NK]        = v0;
        vp[(size_t)(l + 64) * NK] = v1;
    } else {
        float* vp = Vsum + (size_t)b * ND * NK + k;
        vp[(size_t)l * NK]        += v0;
        vp[(size_t)(l + 64) * NK] += v1;
    }
}

extern "C" void kernel_launch(void* const* d_in, const int* in_sizes, int n_in,
                              void* d_out, int out_size, void* d_ws, size_t ws_size,
                              hipStream_t stream) {
    (void)in_sizes; (void)n_in; (void)out_size;
    const float* x = (const float*)d_in[0];
    const float* W = (const float*)d_in[1];
    float* out = (float*)d_out;

    if (ws_size < WS_NEED) return;
    char* ws = (char*)d_ws;
    ushort* u   = (ushort*)ws;
    float* Vsum = (float*)(ws + U_BYTES);
    float* s    = (float*)(ws + U_BYTES + V_BYTES);

    k_zero<<<dim3(256), dim3(256), 0, stream>>>(s);       // 1MB, ~1.5us
    k_u<<<dim3(2048), dim3(256), 0, stream>>>(W, x, u, s);  // + fused pass 1
    k_squash<<<dim3(512), dim3(256), 0, stream>>>(s, Vsum, out, 0);
    k_route<<<dim3(512), dim3(512), 0, stream>>>(u, Vsum, s);
    k_squash<<<dim3(512), dim3(256), 0, stream>>>(s, Vsum, out, 1);
    k_route<<<dim3(512), dim3(512), 0, stream>>>(u, Vsum, s);
    k_squash<<<dim3(512), dim3(256), 0, stream>>>(s, Vsum, out, 2);
}

// Round 11
// 120.768 us; speedup vs baseline: 1.1583x; 1.1583x over previous
//
#include <hip/hip_runtime.h>

#define NB 32
#define NN 64
#define ND 128
#define NE 128
#define NK 64   // output capsules (= NN), contiguous axis of u/Vsum/s

typedef float  f32x4  __attribute__((ext_vector_type(4)));
typedef short  short8 __attribute__((ext_vector_type(8)));
typedef __bf16 bf16x8 __attribute__((ext_vector_type(8)));

union Frag { bf16x8 h; short8 s; };

// u layout: [j][d][b][k]  -- wave-(j,d) output tile is ONE contiguous 4KB run
static constexpr size_t U_BYTES = (size_t)NN * ND * NB * NK * 2;  // 33.5 MB bf16
static constexpr size_t V_BYTES = (size_t)NB * ND * NK * 4;       // 1 MB fp32
static constexpr size_t WS_NEED = U_BYTES + 2 * V_BYTES;

#define GLOAD16(g, l)                                                   \
    __builtin_amdgcn_global_load_lds(                                   \
        (const __attribute__((address_space(1))) void*)(g),             \
        (__attribute__((address_space(3))) void*)(l), 16, 0, 0)

// ---------------- DPP wave64 sum (VALU pipe) ----------------
template <int CTRL, int RMASK>
__device__ __forceinline__ float dppf(float x) {
    int xi = __float_as_int(x);
    return __int_as_float(__builtin_amdgcn_update_dpp(xi, xi, CTRL, RMASK, 0xF, false));
}
__device__ __forceinline__ float wave_sum(float x) {
    x += dppf<0xB1, 0xF>(x);   // quad_perm [1,0,3,2]
    x += dppf<0x4E, 0xF>(x);   // quad_perm [2,3,0,1]
    x += dppf<0x141, 0xF>(x);  // row_half_mirror
    x += dppf<0x140, 0xF>(x);  // row_mirror
    x += dppf<0x142, 0xA>(x);  // row_bcast15 -> rows 1,3
    x += dppf<0x143, 0xC>(x);  // row_bcast31 -> rows 2,3
    return __int_as_float(__builtin_amdgcn_readlane(__float_as_int(x), 63));
}

__device__ __forceinline__ ushort f2bf(float f) {
    __bf16 h = (__bf16)f;
    ushort r;
    __builtin_memcpy(&r, &h, 2);
    return r;
}
__device__ __forceinline__ float bf2f(ushort r) {
    return __int_as_float(((int)r) << 16);
}
__device__ __forceinline__ void cvt8(const float4& a, const float4& b, Frag& fr) {
    fr.h[0] = (__bf16)a.x; fr.h[1] = (__bf16)a.y; fr.h[2] = (__bf16)a.z; fr.h[3] = (__bf16)a.w;
    fr.h[4] = (__bf16)b.x; fr.h[5] = (__bf16)b.y; fr.h[6] = (__bf16)b.z; fr.h[7] = (__bf16)b.w;
}

// ---------------- K1: u[j,d,b,k] = sum_e x[b,j,e] * W[j,k,d,e] (bf16 MFMA) --
// wave = (j,d): M=32 b x N=64 k, K=128 e -> 32 x mfma 16x16x32_bf16.
// W staged global->LDS via global_load_lds; u-write: the wave's [32b][64k]
// tile is ONE contiguous 4KB block (each lane a contiguous 64B run).
__global__ __launch_bounds__(256, 3) void k_u(const float* __restrict__ W,
                                              const float* __restrict__ x,
                                              ushort* __restrict__ u) {
    __shared__ float  Wl[4][2][1024];  // per-wave double-buffered 4KB chunks
    __shared__ ushort T[4][32][72];    // per-wave [b][k] transpose tile
    const int t  = threadIdx.x;
    const int wv = t >> 6;
    const int l  = t & 63;
    const int gw = blockIdx.x * 4 + wv;
    const int j  = gw >> 7;
    const int d  = gw & 127;

    const int lr = l & 15;  // fragment row/col index
    const int lh = l >> 4;  // 0..3
    const int e0 = lh * 8;

    // ---- A fragments: x[b, j, e], row = b (VGPR loads; x is small & L2-hot)
    const float* xb = x + (size_t)j * NE;
    float4 xf[2][4][2];
#pragma unroll
    for (int mt = 0; mt < 2; ++mt)
#pragma unroll
        for (int ec = 0; ec < 4; ++ec) {
            const float* p = xb + (size_t)(mt * 16 + lr) * (NN * NE) + ec * 32 + e0;
            xf[mt][ec][0] = *reinterpret_cast<const float4*>(p);
            xf[mt][ec][1] = *reinterpret_cast<const float4*>(p + 4);
        }
    // drain A-loads so chunk vmcnt bookkeeping below is exact
    asm volatile("s_waitcnt vmcnt(0)" ::: "memory");
    __builtin_amdgcn_sched_barrier(0);
    Frag a[2][4];
#pragma unroll
    for (int mt = 0; mt < 2; ++mt)
#pragma unroll
        for (int ec = 0; ec < 4; ++ec) cvt8(xf[mt][ec][0], xf[mt][ec][1], a[mt][ec]);

    // ---- W staging: chunk c=(nt,eh): k rows nt*16..+15, e floats eh*64..+63
    // LDS e-major: slot = e16*16 + row; instr i, lane l -> slot i*64+l, so
    // source = (row=l&15, e16=i*4+l>>4). 4 x GLOAD16 (1KB each) per chunk.
    const char* Wg = (const char*)W + ((size_t)(j * NN) * ND + d) * (NE * 4);
#define STAGE(c, buf)                                                       \
    {                                                                       \
        const int nt_ = (c) >> 1, eh_ = (c) & 1;                            \
        const char* gp_ = Wg + (size_t)(nt_ * 16 + lr) * 65536 + eh_ * 256; \
        _Pragma("unroll") for (int i_ = 0; i_ < 4; ++i_)                    \
            GLOAD16(gp_ + (i_ * 4 + lh) * 16, &Wl[wv][buf][i_ * 256]);      \
    }

    STAGE(0, 0);
    STAGE(1, 1);

    f32x4 acc[2][4];
#pragma unroll
    for (int mt = 0; mt < 2; ++mt)
#pragma unroll
        for (int nt = 0; nt < 4; ++nt) acc[mt][nt] = (f32x4)0.0f;

#pragma unroll
    for (int c = 0; c < 8; ++c) {
        const int nt = c >> 1, eh = c & 1, buf = c & 1;
        if (c < 7) { asm volatile("s_waitcnt vmcnt(4)" ::: "memory"); }
        else       { asm volatile("s_waitcnt vmcnt(0)" ::: "memory"); }
        __builtin_amdgcn_sched_barrier(0);

        const float* cb = &Wl[wv][buf][0];
        f32x4 g[2][2];
#pragma unroll
        for (int ec = 0; ec < 2; ++ec) {
            const int sl = (ec * 8 + lh * 2) * 64 + lr * 4;
            g[ec][0] = *reinterpret_cast<const f32x4*>(cb + sl);
            g[ec][1] = *reinterpret_cast<const f32x4*>(cb + sl + 64);
        }
        // ds_reads must land before this buffer is re-staged (rule #18)
        asm volatile("s_waitcnt lgkmcnt(0)" ::: "memory");
        __builtin_amdgcn_sched_barrier(0);
        if (c < 6) STAGE(c + 2, buf);

#pragma unroll
        for (int ec = 0; ec < 2; ++ec) {
            Frag bw;
            float4 f0 = {g[ec][0][0], g[ec][0][1], g[ec][0][2], g[ec][0][3]};
            float4 f1 = {g[ec][1][0], g[ec][1][1], g[ec][1][2], g[ec][1][3]};
            cvt8(f0, f1, bw);
#pragma unroll
            for (int mt = 0; mt < 2; ++mt)
                acc[mt][nt] = __builtin_amdgcn_mfma_f32_16x16x32_bf16(
                    a[mt][eh * 2 + ec].s, bw.s, acc[mt][nt], 0, 0, 0);
        }
    }
#undef STAGE

    // D frag: row=b=(l>>4)*4+r (+16*mt), col=k=lr (+16*nt)  [m89 layout]
#pragma unroll
    for (int mt = 0; mt < 2; ++mt)
#pragma unroll
        for (int nt = 0; nt < 4; ++nt)
#pragma unroll
            for (int r = 0; r < 4; ++r)
                T[wv][mt * 16 + lh * 4 + r][nt * 16 + lr] = f2bf(acc[mt][nt][r]);
    __syncthreads();

    // write u[j, d, b, k]: wave tile = 4KB CONTIGUOUS; lane l covers a
    // contiguous 64B run (b = l>>1, k-half = (l&1)*32)
    const int b2 = l >> 1;
    const int kh = (l & 1) * 32;
    ushort* up = u + (((size_t)j * ND + d) * NB + b2) * NK + kh;
    const ushort* tp = &T[wv][b2][kh];
#pragma unroll
    for (int i = 0; i < 4; ++i) {
        short8 v = *reinterpret_cast<const short8*>(tp + i * 8);
        *reinterpret_cast<short8*>(up + i * 8) = v;
    }
}

// ---------------- Routing: s[b,d,k] = sum_j softmax_k(u*Vsum) * u ----------
// block = (b, dg of 8 d); 8 waves = 8 j-groups; lane = k
// u is [j][d][b][k]: each (jj,dd) read is one aligned 128B line (lane=k)
// first=1: logits all zero -> exact uniform softmax, s = sum_j u / 64
__global__ __launch_bounds__(512) void k_route(const ushort* __restrict__ u,
                                               const float* __restrict__ Vsum,
                                               float* __restrict__ s,
                                               int first) {
    __shared__ float P[8][8][65];
    const int b  = blockIdx.x >> 4;
    const int dg = blockIdx.x & 15;
    const int t  = threadIdx.x;
    const int wv = t >> 6;  // j-group
    const int l  = t & 63;  // k

    float sacc[8];
#pragma unroll
    for (int dd = 0; dd < 8; ++dd) sacc[dd] = 0.0f;

    const size_t JS = (size_t)ND * NB * NK;  // j-stride in u
    const ushort* ub = u + ((size_t)(wv * 8) * ND + dg * 8) * (NB * NK) +
                       (size_t)b * NK + l;

    if (first) {
        for (int jj = 0; jj < 8; ++jj) {
            const ushort* up = ub + jj * JS;
#pragma unroll
            for (int dd = 0; dd < 8; ++dd) sacc[dd] += bf2f(up[dd * (NB * NK)]);
        }
#pragma unroll
        for (int dd = 0; dd < 8; ++dd) sacc[dd] *= (1.0f / 64.0f);
    } else {
        float vs[8];
#pragma unroll
        for (int dd = 0; dd < 8; ++dd)
            vs[dd] = Vsum[((size_t)b * ND + dg * 8 + dd) * NK + l];

        for (int jj = 0; jj < 8; ++jj) {
            const ushort* up = ub + jj * JS;
            float uv[8];
#pragma unroll
            for (int dd = 0; dd < 8; ++dd) uv[dd] = bf2f(up[dd * (NB * NK)]);
#pragma unroll
            for (int dd = 0; dd < 8; ++dd) {
                // softmax is shift-invariant; constant shift avoids overflow
                // without a wave_max pass (|logit| realistically < ~45)
                float p = __expf(uv[dd] * vs[dd] - 32.0f);
                float q = wave_sum(p);
                sacc[dd] = fmaf(p * __builtin_amdgcn_rcpf(q), uv[dd], sacc[dd]);
            }
        }
    }

#pragma unroll
    for (int dd = 0; dd < 8; ++dd) P[wv][dd][l] = sacc[dd];
    __syncthreads();

    // 8-way j-group reduce; thread t -> (dd = t>>6, k = t&63)
    const int dd = t >> 6;
    const int k  = t & 63;
    float r = P[0][dd][k];
#pragma unroll
    for (int w2 = 1; w2 < 8; ++w2) r += P[w2][dd][k];
    s[((size_t)b * ND + dg * 8 + dd) * NK + k] = r;
}

// ---------------- Squash: wave=(b,k), lane=d -------------------------------
// mode 0: Vsum = v (init, no read)   mode 1: Vsum += v   mode 2: out = v
__global__ __launch_bounds__(256) void k_squash(const float* __restrict__ s,
                                                float* __restrict__ Vsum,
                                                float* __restrict__ out,
                                                int mode) {
    const int t  = threadIdx.x;
    const int gw = blockIdx.x * 4 + (t >> 6);
    const int b  = gw >> 6;
    const int k  = gw & 63;
    const int l  = t & 63;

    const float s0 = s[((size_t)b * ND + l) * NK + k];
    const float s1 = s[((size_t)b * ND + l + 64) * NK + k];
    float sq    = wave_sum(fmaf(s0, s0, s1 * s1));
    float scale = (sq / (1.0f + sq)) * rsqrtf(sq + 1e-9f);
    float v0 = s0 * scale, v1 = s1 * scale;
    if (mode == 2) {
        float* op = out + ((size_t)b * NN + k) * ND;  // out[b,k,d] contiguous in d
        op[l]      = v0;
        op[l + 64] = v1;
    } else if (mode == 0) {
        float* vp = Vsum + (size_t)b * ND * NK + k;
        vp[(size_t)l * NK]        = v0;
        vp[(size_t)(l + 64) * NK] = v1;
    } else {
        float* vp = Vsum + (size_t)b * ND * NK + k;
        vp[(size_t)l * NK]        += v0;
        vp[(size_t)(l + 64) * NK] += v1;
    }
}

extern "C" void kernel_launch(void* const* d_in, const int* in_sizes, int n_in,
                              void* d_out, int out_size, void* d_ws, size_t ws_size,
                              hipStream_t stream) {
    (void)in_sizes; (void)n_in; (void)out_size;
    const float* x = (const float*)d_in[0];
    const float* W = (const float*)d_in[1];
    float* out = (float*)d_out;

    if (ws_size < WS_NEED) return;
    char* ws = (char*)d_ws;
    ushort* u   = (ushort*)ws;
    float* Vsum = (float*)(ws + U_BYTES);
    float* s    = (float*)(ws + U_BYTES + V_BYTES);

    k_u<<<dim3(2048), dim3(256), 0, stream>>>(W, x, u);
    for (int it = 0; it < 3; ++it) {
        k_route<<<dim3(512), dim3(512), 0, stream>>>(u, Vsum, s, it == 0 ? 1 : 0);
        k_squash<<<dim3(512), dim3(256), 0, stream>>>(s, Vsum, out, it);
    }
}